// Round 9
// baseline (229.070 us; speedup 1.0000x reference)
//
#include <hip/hip_runtime.h>
#include <cstdint>

typedef unsigned short u16;
typedef uint32_t u32;

typedef __bf16 bf16x8 __attribute__((ext_vector_type(8)));
typedef float  f32x2  __attribute__((ext_vector_type(2)));
typedef float  f32x4  __attribute__((ext_vector_type(4)));
typedef float  f32x16 __attribute__((ext_vector_type(16)));
typedef u16    u16x4  __attribute__((ext_vector_type(4)));
typedef u16    u16x8  __attribute__((ext_vector_type(8)));

__device__ __forceinline__ u16 f2bf(float f) {
    u32 x = __float_as_uint(f);
    return (u16)((x + 0x7FFFu + ((x >> 16) & 1u)) >> 16);
}
__device__ __forceinline__ float lrelu(float x) { return fmaxf(x, 0.1f * x); }

// pack two f32 -> dword of two bf16 (round via +0x8000), lo->low16 hi->high16
__device__ __forceinline__ u32 pack_rn(float lo, float hi) {
    u32 a = __float_as_uint(lo) + 0x8000u;
    u32 b = __float_as_uint(hi) + 0x8000u;
    return __builtin_amdgcn_perm(b, a, 0x07060302u);
}

// ---------------------------------------------------------------------------
// Prep: x -> xb bf16 [b][l][e];
//       conv_w -> wcb_f bf16 MFMA-frag order [cb16][ks48][lane64][j8];
//       W2/3/4+b2/3/4 -> wfrag (frag-blocked, bias as 9th K-tile);
//       W1 (i|jx parts) -> W1T4 f32 [cq65][t256][q4];
//       hW[b][d] = h @ W1jh.T;  zero s_glob+stats (replaces memset node).
// ---------------------------------------------------------------------------
__global__ __launch_bounds__(256) void k_prep(
    const float* __restrict__ x, const float* __restrict__ conv_w,
    const float* __restrict__ W2, const float* __restrict__ W3, const float* __restrict__ W4,
    const float* __restrict__ b2, const float* __restrict__ b3, const float* __restrict__ b4,
    const float* __restrict__ h, const float* __restrict__ W1,
    u16* __restrict__ xb, u16* __restrict__ wcb_f, u16* __restrict__ wfrag,
    float* __restrict__ W1T4, float* __restrict__ hW, float* __restrict__ zero0)
{
    int blk = blockIdx.x, tid = threadIdx.x;
    if (blk < 1280) {                       // xb: 1,310,720 elems, 4/thread
        int o = (blk * 256 + tid) * 4;
        int e = o & 511;
        int bl = o >> 9;
        int b = bl / 160, l = bl % 160;
        f32x4 v = *(const f32x4*)(x + ((size_t)(l * 16 + b)) * 512 + e);
        u16x4 ov;
        ov[0] = f2bf(v[0]); ov[1] = f2bf(v[1]); ov[2] = f2bf(v[2]); ov[3] = f2bf(v[3]);
        *(u16x4*)&xb[o] = ov;
    } else if (blk < 1472) {                // wcb_f: 49,152 frags of 16B
        int g = (blk - 1280) * 256 + tid;   // = ((cb*48 + ks)*64 + lane)
        int lane = g & 63;
        int ks = (g >> 6) % 48;
        int cb = g / 3072;
        int c = cb * 16 + (lane & 15);
        int quad = lane >> 4;
        int k0 = ks * 32 + quad * 8;
        int tap = k0 >> 9, e0 = k0 & 511;
        u16x8 ov;
        #pragma unroll
        for (int j = 0; j < 8; j++)
            ov[j] = f2bf(conv_w[((size_t)c * 512 + e0 + j) * 3 + tap]);
        *(u16x8*)&wcb_f[(size_t)g * 8] = ov;
    } else if (blk < 1526) {                // wfrag: 55,296 elems, 54 blocks
        int o = ((blk - 1472) * 256 + tid) * 4;
        int layer = o / 18432, rem = o % 18432;
        int ks9 = rem >> 11;
        int rem2 = rem & 2047;
        int hh = rem2 >> 10;
        int rem3 = rem2 & 1023;
        int n = rem3 >> 3, j0 = rem3 & 7;   // j0 in {0,4}
        const float* W = (layer == 0) ? W2 : (layer == 1) ? W3 : W4;
        const float* bi = (layer == 0) ? b2 : (layer == 1) ? b3 : b4;
        u16x4 ov;
        if (ks9 < 8) {
            f32x4 v = *(const f32x4*)(W + (size_t)n * 128 + 16 * ks9 + 8 * hh + j0);
            ov[0] = f2bf(v[0]); ov[1] = f2bf(v[1]); ov[2] = f2bf(v[2]); ov[3] = f2bf(v[3]);
        } else {
            ov[0] = (hh == 0 && j0 == 0) ? f2bf(bi[n]) : (u16)0;
            ov[1] = 0; ov[2] = 0; ov[3] = 0;
        }
        *(u16x4*)&wfrag[o] = ov;
    } else if (blk < 1591) {                // W1T4: 65 cq-blocks x 256 threads
        int cq = blk - 1526;                // c0 = cq*4
        int t = tid;
        const float* src = (t < 128)
            ? (W1 + (size_t)t * 1028 + cq * 4)
            : (W1 + (size_t)(t - 128) * 1028 + 258 + cq * 4);
        f32x2 v0 = *(const f32x2*)src;
        f32x2 v1 = *(const f32x2*)(src + 2);
        f32x4 v;
        v[0] = v0[0]; v[1] = v0[1];
        v[2] = (cq == 64) ? 0.f : v1[0];
        v[3] = (cq == 64) ? 0.f : v1[1];
        *(f32x4*)&W1T4[((size_t)cq * 256 + t) * 4] = v;
    } else if (blk < 1719) {                // hW: 2048 outs x 16 lanes, 128 blocks
        int gid = (blk - 1591) * 256 + tid;
        int outp = gid >> 4, q = gid & 15;
        int b = outp >> 7, d = outp & 127;
        const float* hr = h + (size_t)b * 512;
        const float* wr = W1 + (size_t)d * 1028 + 516;
        float acc = 0.f;
        #pragma unroll
        for (int c = 0; c < 8; c++) {
            int k = c * 64 + q * 4;
            f32x4 hv = *(const f32x4*)(hr + k);
            f32x4 wv = *(const f32x4*)(wr + k);
            acc += hv[0]*wv[0] + hv[1]*wv[1] + hv[2]*wv[2] + hv[3]*wv[3];
        }
        acc += __shfl_xor(acc, 1); acc += __shfl_xor(acc, 2);
        acc += __shfl_xor(acc, 4); acc += __shfl_xor(acc, 8);
        if (q == 0) hW[outp] = acc;
    } else {                                // zero s_glob(8KB)+stats(2KB): 2560 f
        int idx = (blk - 1719) * 256 + tid;
        if (idx < 640) {
            f32x4 z = {0.f, 0.f, 0.f, 0.f};
            *(f32x4*)&zero0[idx * 4] = z;
        }
    }
}

// ---------------------------------------------------------------------------
// Conv1d (K=3, pad 1) as im2col GEMM, bf16 MFMA. 16-row tiles, 640 WGs.
// ---------------------------------------------------------------------------
__global__ __launch_bounds__(256, 4) void k_conv(
    const u16* __restrict__ xb, const u16* __restrict__ wcb_f,
    const float* __restrict__ conv_b,
    float* __restrict__ ws_y, float* __restrict__ stats)
{
    __shared__ u16 xs[18 * 520];
    int tid = threadIdx.x, wg = blockIdx.x;
    int rowtile = wg >> 2, cg = wg & 3;
    int b = rowtile / 10, l0 = (rowtile % 10) * 16;

    for (int t = tid; t < 18 * 64; t += 256) {
        int s = t >> 6, ch = t & 63;
        int lg = l0 + s - 1;
        u16x8 v = {};
        if (lg >= 0 && lg < 160)
            v = *(const u16x8*)(xb + ((size_t)(b * 160 + lg)) * 512 + ch * 8);
        *(u16x8*)&xs[s * 520 + ch * 8] = v;
    }
    __syncthreads();

    int lane = tid & 63, w = tid >> 6;
    int row16 = lane & 15, quad = lane >> 4;
    int cb = cg * 4 + w;
    int c_n = cb * 16 + row16;
    const u16* wb = wcb_f + (size_t)cb * 24576;   // 48*64*8

    f32x4 acc0 = {0,0,0,0};
    for (int ks4 = 0; ks4 < 48; ks4 += 4) {
        bf16x8 wf[4];
        #pragma unroll
        for (int q = 0; q < 4; q++)
            wf[q] = *(const bf16x8*)(wb + (size_t)((ks4 + q) * 64 + lane) * 8);
        #pragma unroll
        for (int q = 0; q < 4; q++) {
            int k = (ks4 + q) * 32 + quad * 8;
            int tap = k >> 9, e = k & 511;
            bf16x8 a0 = *(const bf16x8*)&xs[(row16 + tap) * 520 + e];
            acc0 = __builtin_amdgcn_mfma_f32_16x16x32_bf16(a0, wf[q], acc0, 0, 0, 0);
        }
    }

    float bias = conv_b[c_n];
    float sum = 0.f, sq = 0.f;
    #pragma unroll
    for (int r = 0; r < 4; r++) {
        float v = lrelu(acc0[r] + bias);
        int lr = l0 + quad * 4 + r;
        ws_y[((size_t)(b * 160 + lr)) * 256 + c_n] = v;
        sum += v; sq += v * v;
    }
    sum += __shfl_xor(sum, 16); sum += __shfl_xor(sum, 32);
    sq  += __shfl_xor(sq, 16);  sq  += __shfl_xor(sq, 32);
    if (quad == 0) {
        atomicAdd(&stats[c_n], sum);
        atomicAdd(&stats[256 + c_n], sq);
    }
}

// ---------------------------------------------------------------------------
// BN + coords -> xf (4 rows, zero-padded to 260), u/v projections with
// coalesced W1T4 loads; 640 WGs.
// ---------------------------------------------------------------------------
__global__ __launch_bounds__(256) void k_uv(
    const float* __restrict__ ws_y, const float* __restrict__ stats,
    const float* __restrict__ bn_g, const float* __restrict__ bn_b,
    const float* __restrict__ W1T4, const float* __restrict__ b1,
    const float* __restrict__ hW,
    float* __restrict__ uu, float* __restrict__ vv)
{
    __shared__ float a_s[256], c_s[256];
    __shared__ float xfs[4 * 260];
    int tid = threadIdx.x;
    int row0 = blockIdx.x * 4;
    int b = row0 / 160, l0 = row0 % 160;
    {
        int c = tid;
        float mu  = stats[c] * (1.0f / 2560.0f);
        float var = stats[256 + c] * (1.0f / 2560.0f) - mu * mu;
        float rs  = rsqrtf(var + 1e-5f) * bn_g[c];
        a_s[c] = rs;
        c_s[c] = bn_b[c] - mu * rs;
    }
    __syncthreads();
    float sLf = sqrtf(160.0f);
    for (int idx = tid; idx < 4 * 260; idx += 256) {
        int r = idx / 260, c = idx - r * 260;
        int l = l0 + r;
        float v = 0.f;
        if (c < 256) {
            v = ws_y[((size_t)(b * 160 + l)) * 256 + c] * a_s[c] + c_s[c];
        } else if (c == 256) {
            v = ((float)l / sLf - 2.0f) * 0.5f;
        } else if (c == 257) {
            float fi = (float)l;
            float m = fi - floorf(fi / sLf) * sLf;
            v = (m - 2.0f) * 0.5f;
        }
        xfs[r * 260 + c] = v;
    }
    __syncthreads();

    float acc[4] = {0,0,0,0};
    #pragma unroll 4
    for (int cq = 0; cq < 65; cq++) {
        f32x4 w4 = *(const f32x4*)&W1T4[((size_t)cq * 256 + tid) * 4];
        #pragma unroll
        for (int r = 0; r < 4; r++) {
            f32x4 xv = *(const f32x4*)&xfs[r * 260 + cq * 4];
            acc[r] += w4[0]*xv[0] + w4[1]*xv[1] + w4[2]*xv[2] + w4[3]*xv[3];
        }
    }

    bool isv = tid >= 128;
    int d = tid & 127;
    float vadd = isv ? (hW[b * 128 + d] + b1[d]) : 0.f;
    float* dst = isv ? vv : uu;
    #pragma unroll
    for (int r = 0; r < 4; r++)
        dst[((size_t)(b * 160 + l0 + r)) * 128 + d] = acc[r] + vadd;
}

// ---------------------------------------------------------------------------
// Fused pairwise MLP v8 — T=2: each wave owns TWO 32-pair tiles so every
// W-frag ds_read feeds 2 MFMAs (LDS-port floor halves to ~25 µs). z for both
// tiles in registers (B0/B1), next-layer z double-buffered (N0/N1) and
// swapped after the nt loop. Per-nt chains, first MFMA takes Z (no re-init).
// __launch_bounds__(256,2): ~190 regs/wave fits 2 waves/SIMD, spill-free.
// Layers 0,1: D=W(A) x z^T(B); layer 2 flipped: D=z(A) x W(B), in-lane sum.
// Bias via 9th K-tile. Grid: 1600 WGs = 16 b x 100; tiles = sub*8+wave*2+{0,1}.
// ---------------------------------------------------------------------------
__global__ __launch_bounds__(256, 2) void k_mlp(
    const float* __restrict__ vv, const float* __restrict__ uu,
    const u16* __restrict__ wfrag,
    float* __restrict__ s_glob)
{
    __shared__ __align__(16) u16 Wlds[18432];   // [ks9][h][n][8]
    __shared__ float spart[128];
    int tid = threadIdx.x;
    int wave = tid >> 6, lane = tid & 63;
    int h = lane >> 5, lo = lane & 31;
    int b = blockIdx.x / 100, sub = blockIdx.x % 100;
    int t0 = sub * 8 + wave * 2;

    if (tid < 128) spart[tid] = 0.f;

    u32 selv = h ? 0x07060302u : 0x05040100u;
    uint4 biasfrag;
    biasfrag.x = (h == 0) ? 0x00003F80u : 0u;   // bf16 1.0 at j=0, h=0
    biasfrag.y = 0u; biasfrag.z = 0u; biasfrag.w = 0u;

    f32x16 Z;
    #pragma unroll
    for (int r = 0; r < 16; r++) Z[r] = 0.f;

    uint4 B0[8], B1[8], N0[8], N1[8];
    float ssum[2][4];

    int ta = t0, tb = t0 + 1;
    int ia = (ta / 10) * 2 + (lo >> 4), ja = (ta % 10) * 16 + (lo & 15);
    int ib = (tb / 10) * 2 + (lo >> 4), jb = (tb % 10) * 16 + (lo & 15);
    const float* vra = vv + ((size_t)(b * 160 + ia)) * 128 + 8 * h;
    const float* ura = uu + ((size_t)(b * 160 + ja)) * 128 + 8 * h;
    const float* vrb = vv + ((size_t)(b * 160 + ib)) * 128 + 8 * h;
    const float* urb = uu + ((size_t)(b * 160 + jb)) * 128 + 8 * h;

    for (int layer = 0; layer < 3; layer++) {
        __syncthreads();                    // prior readers done
        {   // stage this layer's weights: 2304 x 16B
            const uint4* src = (const uint4*)(wfrag + layer * 18432);
            #pragma unroll
            for (int it = 0; it < 9; it++) {
                int idx = it * 256 + tid;
                *(uint4*)&Wlds[idx * 8] = src[idx];
            }
        }
        __syncthreads();                    // weights visible

        if (layer == 0) {
            // build z0 frags for both tiles: z0[m=lo][k] = lrelu(v_i + u_j)
            #pragma unroll
            for (int ks = 0; ks < 8; ks++) {
                f32x4 v0 = *(const f32x4*)(vra + 16 * ks);
                f32x4 v1 = *(const f32x4*)(vra + 16 * ks + 4);
                f32x4 u0 = *(const f32x4*)(ura + 16 * ks);
                f32x4 u1 = *(const f32x4*)(ura + 16 * ks + 4);
                uint4 d;
                d.x = pack_rn(lrelu(v0[0]+u0[0]), lrelu(v0[1]+u0[1]));
                d.y = pack_rn(lrelu(v0[2]+u0[2]), lrelu(v0[3]+u0[3]));
                d.z = pack_rn(lrelu(v1[0]+u1[0]), lrelu(v1[1]+u1[1]));
                d.w = pack_rn(lrelu(v1[2]+u1[2]), lrelu(v1[3]+u1[3]));
                B0[ks] = d;
                f32x4 w0 = *(const f32x4*)(vrb + 16 * ks);
                f32x4 w1 = *(const f32x4*)(vrb + 16 * ks + 4);
                f32x4 y0 = *(const f32x4*)(urb + 16 * ks);
                f32x4 y1 = *(const f32x4*)(urb + 16 * ks + 4);
                uint4 e;
                e.x = pack_rn(lrelu(w0[0]+y0[0]), lrelu(w0[1]+y0[1]));
                e.y = pack_rn(lrelu(w0[2]+y0[2]), lrelu(w0[3]+y0[3]));
                e.z = pack_rn(lrelu(w1[0]+y1[0]), lrelu(w1[1]+y1[1]));
                e.w = pack_rn(lrelu(w1[2]+y1[2]), lrelu(w1[3]+y1[3]));
                B1[ks] = e;
            }
        }

        #pragma unroll
        for (int nt = 0; nt < 4; nt++) {
            f32x16 a0, a1;
            #pragma unroll
            for (int ks = 0; ks < 9; ks++) {
                bf16x8 wf = *(const bf16x8*)&Wlds[(size_t)(ks * 256 + h * 128 + nt * 32 + lo) * 8];
                uint4 z0u = (ks < 8) ? B0[ks] : biasfrag;
                uint4 z1u = (ks < 8) ? B1[ks] : biasfrag;
                bf16x8 zf0 = *(bf16x8*)&z0u;
                bf16x8 zf1 = *(bf16x8*)&z1u;
                if (layer < 2) {
                    a0 = __builtin_amdgcn_mfma_f32_32x32x16_bf16(wf, zf0, ks ? a0 : Z, 0, 0, 0);
                    a1 = __builtin_amdgcn_mfma_f32_32x32x16_bf16(wf, zf1, ks ? a1 : Z, 0, 0, 0);
                } else {
                    a0 = __builtin_amdgcn_mfma_f32_32x32x16_bf16(zf0, wf, ks ? a0 : Z, 0, 0, 0);
                    a1 = __builtin_amdgcn_mfma_f32_32x32x16_bf16(zf1, wf, ks ? a1 : Z, 0, 0, 0);
                }
            }

            if (layer < 2) {
                // C-layout -> z-frag layout, per slot, into N buffers
                #pragma unroll
                for (int s = 0; s < 2; s++) {
                    const f32x16& a = s ? a1 : a0;
                    u32 own[4][2], oth[4][2];
                    #pragma unroll
                    for (int c = 0; c < 4; c++)
                        #pragma unroll
                        for (int p = 0; p < 2; p++)
                            own[c][p] = pack_rn(lrelu(a[c + 8*p]),
                                                lrelu(a[c + 4 + 8*p]));
                    #pragma unroll
                    for (int c = 0; c < 4; c++)
                        #pragma unroll
                        for (int p = 0; p < 2; p++)
                            oth[c][p] = (u32)__shfl_xor((int)own[c][p], 32);
                    #pragma unroll
                    for (int p = 0; p < 2; p++) {
                        u32 dA0 = __builtin_amdgcn_perm(own[1][p], own[0][p], selv);
                        u32 dB0 = __builtin_amdgcn_perm(oth[1][p], oth[0][p], selv);
                        u32 dA1 = __builtin_amdgcn_perm(own[3][p], own[2][p], selv);
                        u32 dB1 = __builtin_amdgcn_perm(oth[3][p], oth[2][p], selv);
                        uint4 d;
                        d.x = h ? dB0 : dA0;
                        d.y = h ? dB1 : dA1;
                        d.z = h ? dA0 : dB0;
                        d.w = h ? dA1 : dB1;
                        if (s) N1[2 * nt + p] = d; else N0[2 * nt + p] = d;
                    }
                }
            } else {
                float s0 = 0.f, s1 = 0.f;
                #pragma unroll
                for (int r = 0; r < 16; r++) {
                    s0 += lrelu(a0[r]);
                    s1 += lrelu(a1[r]);
                }
                ssum[0][nt] = s0;
                ssum[1][nt] = s1;
            }
        }

        if (layer < 2) {
            #pragma unroll
            for (int ks = 0; ks < 8; ks++) { B0[ks] = N0[ks]; B1[ks] = N1[ks]; }
        }
    }

    // combine slots + h-halves; lane lo owns feature n = nt*32+lo
    #pragma unroll
    for (int nt = 0; nt < 4; nt++) {
        float v = ssum[0][nt] + ssum[1][nt];
        v += __shfl_xor(v, 32);
        if (h == 0) atomicAdd(&spart[nt * 32 + lo], v);
    }
    __syncthreads();
    if (tid < 128) atomicAdd(&s_glob[b * 128 + tid], spart[tid]);
}

// ---------------------------------------------------------------------------
// Final: s -> lrelu(W5) -> lrelu(W6) -> out. One WG (256 thr) per batch,
// thread-per-output dot products (W rows are L2-hot).
// ---------------------------------------------------------------------------
__global__ __launch_bounds__(256) void k_final(
    const float* __restrict__ s_glob,
    const float* __restrict__ W5, const float* __restrict__ b5,
    const float* __restrict__ W6, const float* __restrict__ b6,
    float* __restrict__ out)
{
    __shared__ float sh[128], t5[128];
    int b = blockIdx.x, tid = threadIdx.x;
    if (tid < 128) sh[tid] = s_glob[b * 128 + tid];
    __syncthreads();
    if (tid < 128) {
        const float* wr = W5 + (size_t)tid * 128;
        float acc = b5[tid];
        #pragma unroll
        for (int k = 0; k < 128; k += 4) {
            f32x4 wv = *(const f32x4*)(wr + k);
            f32x4 sv = *(const f32x4*)&sh[k];
            acc += wv[0]*sv[0] + wv[1]*sv[1] + wv[2]*sv[2] + wv[3]*sv[3];
        }
        t5[tid] = lrelu(acc);
    }
    __syncthreads();
    #pragma unroll
    for (int q = 0; q < 2; q++) {
        int o = q * 256 + tid;
        const float* wr = W6 + (size_t)o * 128;
        float acc = b6[o];
        #pragma unroll
        for (int k = 0; k < 128; k += 4) {
            f32x4 wv = *(const f32x4*)(wr + k);
            f32x4 tv = *(const f32x4*)&t5[k];
            acc += wv[0]*tv[0] + wv[1]*tv[1] + wv[2]*tv[2] + wv[3]*tv[3];
        }
        out[b * 512 + o] = lrelu(acc);
    }
}

// ---------------------------------------------------------------------------
extern "C" void kernel_launch(void* const* d_in, const int* in_sizes, int n_in,
                              void* d_out, int out_size, void* d_ws, size_t ws_size,
                              hipStream_t stream)
{
    const float* x      = (const float*)d_in[0];
    const float* h      = (const float*)d_in[1];
    const float* conv_w = (const float*)d_in[2];
    const float* conv_b = (const float*)d_in[3];
    const float* bn_g   = (const float*)d_in[4];
    const float* bn_b   = (const float*)d_in[5];
    const float* W1     = (const float*)d_in[6];
    const float* b1     = (const float*)d_in[7];
    const float* W2     = (const float*)d_in[8];
    const float* b2     = (const float*)d_in[9];
    const float* W3     = (const float*)d_in[10];
    const float* b3     = (const float*)d_in[11];
    const float* W4     = (const float*)d_in[12];
    const float* b4     = (const float*)d_in[13];
    const float* W5     = (const float*)d_in[14];
    const float* b5     = (const float*)d_in[15];
    const float* W6     = (const float*)d_in[16];
    const float* b6     = (const float*)d_in[17];

    char* ws = (char*)d_ws;
    float* s_glob = (float*)(ws + 0);          //  8 KB
    float* stats  = (float*)(ws + 8192);       //  2 KB
    float* hW     = (float*)(ws + 10240);      //  8 KB
    float* ws_y   = (float*)(ws + 18432);      //  2.62 MB
    float* vv     = (float*)(ws + 2639872);    //  1.31 MB
    float* uu     = (float*)(ws + 3950592);    //  1.31 MB
    u16*   xb     = (u16*)  (ws + 5261312);    //  2.62 MB
    u16*   wcb_f  = (u16*)  (ws + 7882752);    //  786 KB (frag order)
    u16*   wfrag  = (u16*)  (ws + 8669184);    //  110.6 KB
    float* W1T4   = (float*)(ws + 8779776);    //  266 KB (end 9,046,016)

    k_prep <<<1722, 256, 0, stream>>>(x, conv_w, W2, W3, W4, b2, b3, b4, h, W1,
                                      xb, wcb_f, wfrag, W1T4, hW, s_glob);
    k_conv <<<640, 256, 0, stream>>>(xb, wcb_f, conv_b, ws_y, stats);
    k_uv   <<<640, 256, 0, stream>>>(ws_y, stats, bn_g, bn_b, W1T4, b1, hW, uu, vv);
    k_mlp  <<<1600, 256, 0, stream>>>(vv, uu, wfrag, s_glob);
    k_final<<<16, 256, 0, stream>>>(s_glob, W5, b5, W6, b6, (float*)d_out);
}

// Round 10
// 193.165 us; speedup vs baseline: 1.1859x; 1.1859x over previous
//
#include <hip/hip_runtime.h>
#include <cstdint>

typedef unsigned short u16;
typedef uint32_t u32;

typedef __bf16 bf16x8 __attribute__((ext_vector_type(8)));
typedef float  f32x2  __attribute__((ext_vector_type(2)));
typedef float  f32x4  __attribute__((ext_vector_type(4)));
typedef float  f32x16 __attribute__((ext_vector_type(16)));
typedef u16    u16x4  __attribute__((ext_vector_type(4)));
typedef u16    u16x8  __attribute__((ext_vector_type(8)));

__device__ __forceinline__ u16 f2bf(float f) {
    u32 x = __float_as_uint(f);
    return (u16)((x + 0x7FFFu + ((x >> 16) & 1u)) >> 16);
}
__device__ __forceinline__ float lrelu(float x) { return fmaxf(x, 0.1f * x); }

// pack two f32 -> dword of two bf16 (round via +0x8000), lo->low16 hi->high16
__device__ __forceinline__ u32 pack_rn(float lo, float hi) {
    u32 a = __float_as_uint(lo) + 0x8000u;
    u32 b = __float_as_uint(hi) + 0x8000u;
    return __builtin_amdgcn_perm(b, a, 0x07060302u);
}

// ---------------------------------------------------------------------------
// Prep: x -> xb bf16 [b][l][e];
//       conv_w -> wcb_f bf16 MFMA-frag order [cb16][ks48][lane64][j8];
//       W2/3/4+b2/3/4 -> wfrag (frag-blocked, bias as 9th K-tile);
//       W1 (i|jx) -> w1frag bf16 B-frag order [nt16][ks9][lane64][j8], K 258->288;
//       hW[b][d] = h @ W1jh.T;  zero s_glob+stats.
// ---------------------------------------------------------------------------
__global__ __launch_bounds__(256) void k_prep(
    const float* __restrict__ x, const float* __restrict__ conv_w,
    const float* __restrict__ W2, const float* __restrict__ W3, const float* __restrict__ W4,
    const float* __restrict__ b2, const float* __restrict__ b3, const float* __restrict__ b4,
    const float* __restrict__ h, const float* __restrict__ W1,
    u16* __restrict__ xb, u16* __restrict__ wcb_f, u16* __restrict__ wfrag,
    u16* __restrict__ w1frag, float* __restrict__ hW, float* __restrict__ zero0)
{
    int blk = blockIdx.x, tid = threadIdx.x;
    if (blk < 1280) {                       // xb: 1,310,720 elems, 4/thread
        int o = (blk * 256 + tid) * 4;
        int e = o & 511;
        int bl = o >> 9;
        int b = bl / 160, l = bl % 160;
        f32x4 v = *(const f32x4*)(x + ((size_t)(l * 16 + b)) * 512 + e);
        u16x4 ov;
        ov[0] = f2bf(v[0]); ov[1] = f2bf(v[1]); ov[2] = f2bf(v[2]); ov[3] = f2bf(v[3]);
        *(u16x4*)&xb[o] = ov;
    } else if (blk < 1472) {                // wcb_f: 49,152 frags of 16B
        int g = (blk - 1280) * 256 + tid;   // = ((cb*48 + ks)*64 + lane)
        int lane = g & 63;
        int ks = (g >> 6) % 48;
        int cb = g / 3072;
        int c = cb * 16 + (lane & 15);
        int quad = lane >> 4;
        int k0 = ks * 32 + quad * 8;
        int tap = k0 >> 9, e0 = k0 & 511;
        u16x8 ov;
        #pragma unroll
        for (int j = 0; j < 8; j++)
            ov[j] = f2bf(conv_w[((size_t)c * 512 + e0 + j) * 3 + tap]);
        *(u16x8*)&wcb_f[(size_t)g * 8] = ov;
    } else if (blk < 1526) {                // wfrag: 55,296 elems, 54 blocks
        int o = ((blk - 1472) * 256 + tid) * 4;
        int layer = o / 18432, rem = o % 18432;
        int ks9 = rem >> 11;
        int rem2 = rem & 2047;
        int hh = rem2 >> 10;
        int rem3 = rem2 & 1023;
        int n = rem3 >> 3, j0 = rem3 & 7;   // j0 in {0,4}
        const float* W = (layer == 0) ? W2 : (layer == 1) ? W3 : W4;
        const float* bi = (layer == 0) ? b2 : (layer == 1) ? b3 : b4;
        u16x4 ov;
        if (ks9 < 8) {
            f32x4 v = *(const f32x4*)(W + (size_t)n * 128 + 16 * ks9 + 8 * hh + j0);
            ov[0] = f2bf(v[0]); ov[1] = f2bf(v[1]); ov[2] = f2bf(v[2]); ov[3] = f2bf(v[3]);
        } else {
            ov[0] = (hh == 0 && j0 == 0) ? f2bf(bi[n]) : (u16)0;
            ov[1] = 0; ov[2] = 0; ov[3] = 0;
        }
        *(u16x4*)&wfrag[o] = ov;
    } else if (blk < 1598) {                // w1frag: 73,728 elems, 72 blocks
        int o = ((blk - 1526) * 256 + tid) * 4;
        int nt = o / 4608;                  // 9*64*8
        int rem = o % 4608;
        int ks = rem >> 9;
        int rem2 = rem & 511;
        int lane = rem2 >> 3, j0 = rem2 & 7;
        int n = nt * 16 + (lane & 15);
        int k0 = ks * 32 + (lane >> 4) * 8 + j0;
        const float* wr = (n < 128) ? (W1 + (size_t)n * 1028)
                                    : (W1 + (size_t)(n - 128) * 1028 + 258);
        u16x4 ov;
        #pragma unroll
        for (int q = 0; q < 4; q++) {
            int k = k0 + q;
            ov[q] = (k < 258) ? f2bf(wr[k]) : (u16)0;
        }
        *(u16x4*)&w1frag[o] = ov;
    } else if (blk < 1726) {                // hW: 2048 outs x 16 lanes, 128 blocks
        int gid = (blk - 1598) * 256 + tid;
        int outp = gid >> 4, q = gid & 15;
        int b = outp >> 7, d = outp & 127;
        const float* hr = h + (size_t)b * 512;
        const float* wr = W1 + (size_t)d * 1028 + 516;
        float acc = 0.f;
        #pragma unroll
        for (int c = 0; c < 8; c++) {
            int k = c * 64 + q * 4;
            f32x4 hv = *(const f32x4*)(hr + k);
            f32x4 wv = *(const f32x4*)(wr + k);
            acc += hv[0]*wv[0] + hv[1]*wv[1] + hv[2]*wv[2] + hv[3]*wv[3];
        }
        acc += __shfl_xor(acc, 1); acc += __shfl_xor(acc, 2);
        acc += __shfl_xor(acc, 4); acc += __shfl_xor(acc, 8);
        if (q == 0) hW[outp] = acc;
    } else {                                // zero s_glob(8KB)+stats(2KB): 2560 f
        int idx = (blk - 1726) * 256 + tid;
        if (idx < 640) {
            f32x4 z = {0.f, 0.f, 0.f, 0.f};
            *(f32x4*)&zero0[idx * 4] = z;
        }
    }
}

// ---------------------------------------------------------------------------
// Conv1d (K=3, pad 1) as im2col GEMM, bf16 MFMA. 16-row tiles, 640 WGs.
// ---------------------------------------------------------------------------
__global__ __launch_bounds__(256, 4) void k_conv(
    const u16* __restrict__ xb, const u16* __restrict__ wcb_f,
    const float* __restrict__ conv_b,
    float* __restrict__ ws_y, float* __restrict__ stats)
{
    __shared__ u16 xs[18 * 520];
    int tid = threadIdx.x, wg = blockIdx.x;
    int rowtile = wg >> 2, cg = wg & 3;
    int b = rowtile / 10, l0 = (rowtile % 10) * 16;

    for (int t = tid; t < 18 * 64; t += 256) {
        int s = t >> 6, ch = t & 63;
        int lg = l0 + s - 1;
        u16x8 v = {};
        if (lg >= 0 && lg < 160)
            v = *(const u16x8*)(xb + ((size_t)(b * 160 + lg)) * 512 + ch * 8);
        *(u16x8*)&xs[s * 520 + ch * 8] = v;
    }
    __syncthreads();

    int lane = tid & 63, w = tid >> 6;
    int row16 = lane & 15, quad = lane >> 4;
    int cb = cg * 4 + w;
    int c_n = cb * 16 + row16;
    const u16* wb = wcb_f + (size_t)cb * 24576;   // 48*64*8

    f32x4 acc0 = {0,0,0,0};
    for (int ks4 = 0; ks4 < 48; ks4 += 4) {
        bf16x8 wf[4];
        #pragma unroll
        for (int q = 0; q < 4; q++)
            wf[q] = *(const bf16x8*)(wb + (size_t)((ks4 + q) * 64 + lane) * 8);
        #pragma unroll
        for (int q = 0; q < 4; q++) {
            int k = (ks4 + q) * 32 + quad * 8;
            int tap = k >> 9, e = k & 511;
            bf16x8 a0 = *(const bf16x8*)&xs[(row16 + tap) * 520 + e];
            acc0 = __builtin_amdgcn_mfma_f32_16x16x32_bf16(a0, wf[q], acc0, 0, 0, 0);
        }
    }

    float bias = conv_b[c_n];
    float sum = 0.f, sq = 0.f;
    #pragma unroll
    for (int r = 0; r < 4; r++) {
        float v = lrelu(acc0[r] + bias);
        int lr = l0 + quad * 4 + r;
        ws_y[((size_t)(b * 160 + lr)) * 256 + c_n] = v;
        sum += v; sq += v * v;
    }
    sum += __shfl_xor(sum, 16); sum += __shfl_xor(sum, 32);
    sq  += __shfl_xor(sq, 16);  sq  += __shfl_xor(sq, 32);
    if (quad == 0) {
        atomicAdd(&stats[c_n], sum);
        atomicAdd(&stats[256 + c_n], sq);
    }
}

// ---------------------------------------------------------------------------
// k_uv v2 — MFMA GEMM: u|v = xf @ W1T via 16x16x32 bf16.
// xf (BN output + coords, K padded 258->288 with zeros) staged bf16 in LDS;
// W1 read as pre-built B-frags (w1frag, L2-hot). 16 rows/WG, 160 WGs;
// wave w covers n = w*64..w*64+63 (4 n-tiles). fp32 epilogue adds hW+b1 to v.
// ---------------------------------------------------------------------------
__global__ __launch_bounds__(256) void k_uv(
    const float* __restrict__ ws_y, const float* __restrict__ stats,
    const float* __restrict__ bn_g, const float* __restrict__ bn_b,
    const u16* __restrict__ w1frag, const float* __restrict__ b1,
    const float* __restrict__ hW,
    float* __restrict__ uu, float* __restrict__ vv)
{
    __shared__ float a_s[256], c_s[256];
    __shared__ __align__(16) u16 xfs[16 * 296];   // 16 rows x 288 (+8 pad)
    int tid = threadIdx.x;
    int row0 = blockIdx.x * 16;
    int b = row0 / 160, l0 = row0 % 160;
    {
        int c = tid;
        float mu  = stats[c] * (1.0f / 2560.0f);
        float var = stats[256 + c] * (1.0f / 2560.0f) - mu * mu;
        float rs  = rsqrtf(var + 1e-5f) * bn_g[c];
        a_s[c] = rs;
        c_s[c] = bn_b[c] - mu * rs;
    }
    __syncthreads();
    float sLf = sqrtf(160.0f);
    for (int idx = tid; idx < 16 * 288; idx += 256) {
        int r = idx / 288, c = idx - r * 288;
        int l = l0 + r;
        float v = 0.f;
        if (c < 256) {
            v = ws_y[((size_t)(b * 160 + l)) * 256 + c] * a_s[c] + c_s[c];
        } else if (c == 256) {
            v = ((float)l / sLf - 2.0f) * 0.5f;
        } else if (c == 257) {
            float fi = (float)l;
            float m = fi - floorf(fi / sLf) * sLf;
            v = (m - 2.0f) * 0.5f;
        }
        xfs[r * 296 + c] = f2bf(v);
    }
    __syncthreads();

    int lane = tid & 63, w = tid >> 6;
    int row16 = lane & 15, quad = lane >> 4;

    bf16x8 af[9];
    #pragma unroll
    for (int ks = 0; ks < 9; ks++)
        af[ks] = *(const bf16x8*)&xfs[row16 * 296 + ks * 32 + quad * 8];

    f32x4 acc[4];
    #pragma unroll
    for (int nt = 0; nt < 4; nt++) {
        f32x4 a = {0.f, 0.f, 0.f, 0.f};
        #pragma unroll
        for (int ks = 0; ks < 9; ks++) {
            bf16x8 bf = *(const bf16x8*)(w1frag +
                (size_t)(((w * 4 + nt) * 9 + ks) * 64 + lane) * 8);
            a = __builtin_amdgcn_mfma_f32_16x16x32_bf16(af[ks], bf, a, 0, 0, 0);
        }
        acc[nt] = a;
    }

    #pragma unroll
    for (int nt = 0; nt < 4; nt++) {
        int n = (w * 4 + nt) * 16 + row16;   // C col = lane&15
        bool isv = n >= 128;
        int d = n & 127;
        float add = isv ? (hW[b * 128 + d] + b1[d]) : 0.f;
        float* dst = isv ? vv : uu;
        #pragma unroll
        for (int r = 0; r < 4; r++) {
            int l = l0 + quad * 4 + r;       // C row = quad*4 + r
            dst[((size_t)(b * 160 + l)) * 128 + d] = acc[nt][r] + add;
        }
    }
}

// ---------------------------------------------------------------------------
// Fused pairwise MLP v5 (round-6 revert — empirical best: 77 µs, VGPR 64,
// zero spills). T=1 tile/wave, per-nt sequential chains, Bn swap buffer,
// __launch_bounds__(256,4): 16 waves/CU, LDS 37KB x 4 WG.
// Layers 0,1: D=W(A) x z^T(B); layer 2 flipped: D=z(A) x W(B), in-lane sum.
// Bias via 9th K-tile. Grid: 3200 WGs = 16 b x 200; 1 tile/wave.
// ---------------------------------------------------------------------------
__global__ __launch_bounds__(256, 4) void k_mlp(
    const float* __restrict__ vv, const float* __restrict__ uu,
    const u16* __restrict__ wfrag,
    float* __restrict__ s_glob)
{
    __shared__ __align__(16) u16 Wlds[18432];   // [ks9][h][n][8]
    __shared__ float spart[128];
    int tid = threadIdx.x;
    int wave = tid >> 6, lane = tid & 63;
    int h = lane >> 5, lo = lane & 31;
    int b = blockIdx.x / 200, sub = blockIdx.x % 200;
    int tileb = sub * 4 + wave;

    if (tid < 128) spart[tid] = 0.f;

    u32 selv = h ? 0x07060302u : 0x05040100u;
    uint4 biasfrag;
    biasfrag.x = (h == 0) ? 0x00003F80u : 0u;   // bf16 1.0 at j=0, h=0
    biasfrag.y = 0u; biasfrag.z = 0u; biasfrag.w = 0u;

    f32x16 Z;
    #pragma unroll
    for (int r = 0; r < 16; r++) Z[r] = 0.f;

    uint4 B[8], Bn[8];          // z-frags (bf16 packed), current/next
    float ssum[4];

    int i  = (tileb / 10) * 2  + (lo >> 4);
    int jj = (tileb % 10) * 16 + (lo & 15);
    const float* vr = vv + ((size_t)(b * 160 + i))  * 128 + 8 * h;
    const float* ur = uu + ((size_t)(b * 160 + jj)) * 128 + 8 * h;

    for (int layer = 0; layer < 3; layer++) {
        __syncthreads();                    // prior readers done
        {   // stage this layer's weights: 2304 x 16B
            const uint4* src = (const uint4*)(wfrag + layer * 18432);
            #pragma unroll
            for (int it = 0; it < 9; it++) {
                int idx = it * 256 + tid;
                *(uint4*)&Wlds[idx * 8] = src[idx];
            }
        }
        __syncthreads();                    // weights visible

        if (layer == 0) {
            // build z0 frags: z0[m=lo][k] = lrelu(v_i + u_j)
            #pragma unroll
            for (int ks = 0; ks < 8; ks++) {
                f32x4 v0 = *(const f32x4*)(vr + 16 * ks);
                f32x4 v1 = *(const f32x4*)(vr + 16 * ks + 4);
                f32x4 u0 = *(const f32x4*)(ur + 16 * ks);
                f32x4 u1 = *(const f32x4*)(ur + 16 * ks + 4);
                uint4 d;
                d.x = pack_rn(lrelu(v0[0]+u0[0]), lrelu(v0[1]+u0[1]));
                d.y = pack_rn(lrelu(v0[2]+u0[2]), lrelu(v0[3]+u0[3]));
                d.z = pack_rn(lrelu(v1[0]+u1[0]), lrelu(v1[1]+u1[1]));
                d.w = pack_rn(lrelu(v1[2]+u1[2]), lrelu(v1[3]+u1[3]));
                B[ks] = d;
            }
        }

        #pragma unroll
        for (int nt = 0; nt < 4; nt++) {
            f32x16 a;
            #pragma unroll
            for (int ks = 0; ks < 9; ks++) {
                bf16x8 wf = *(const bf16x8*)&Wlds[(size_t)(ks * 256 + h * 128 + nt * 32 + lo) * 8];
                uint4 zu = (ks < 8) ? B[ks] : biasfrag;
                bf16x8 zf = *(bf16x8*)&zu;
                if (layer < 2)
                    a = __builtin_amdgcn_mfma_f32_32x32x16_bf16(wf, zf, ks ? a : Z, 0, 0, 0);
                else
                    a = __builtin_amdgcn_mfma_f32_32x32x16_bf16(zf, wf, ks ? a : Z, 0, 0, 0);
            }

            if (layer < 2) {
                // C-layout -> z-frag layout, in-register (per-nt local)
                u32 own[4][2], oth[4][2];
                #pragma unroll
                for (int c = 0; c < 4; c++)
                    #pragma unroll
                    for (int p = 0; p < 2; p++)
                        own[c][p] = pack_rn(lrelu(a[c + 8*p]),
                                            lrelu(a[c + 4 + 8*p]));
                #pragma unroll
                for (int c = 0; c < 4; c++)
                    #pragma unroll
                    for (int p = 0; p < 2; p++)
                        oth[c][p] = (u32)__shfl_xor((int)own[c][p], 32);
                #pragma unroll
                for (int p = 0; p < 2; p++) {
                    u32 dA0 = __builtin_amdgcn_perm(own[1][p], own[0][p], selv);
                    u32 dB0 = __builtin_amdgcn_perm(oth[1][p], oth[0][p], selv);
                    u32 dA1 = __builtin_amdgcn_perm(own[3][p], own[2][p], selv);
                    u32 dB1 = __builtin_amdgcn_perm(oth[3][p], oth[2][p], selv);
                    uint4 d;
                    d.x = h ? dB0 : dA0;
                    d.y = h ? dB1 : dA1;
                    d.z = h ? dA0 : dB0;
                    d.w = h ? dA1 : dB1;
                    Bn[2 * nt + p] = d;
                }
            } else {
                float t = 0.f;
                #pragma unroll
                for (int r = 0; r < 16; r++)
                    t += lrelu(a[r]);
                ssum[nt] = t;
            }
        }

        if (layer < 2) {
            #pragma unroll
            for (int ks = 0; ks < 8; ks++) B[ks] = Bn[ks];
        }
    }

    // combine h-halves (m 0..31) and flush: lane lo owns feature n = nt*32+lo
    #pragma unroll
    for (int nt = 0; nt < 4; nt++) {
        float v = ssum[nt] + __shfl_xor(ssum[nt], 32);
        if (h == 0) atomicAdd(&spart[nt * 32 + lo], v);
    }
    __syncthreads();
    if (tid < 128) atomicAdd(&s_glob[b * 128 + tid], spart[tid]);
}

// ---------------------------------------------------------------------------
// Final: s -> lrelu(W5) -> lrelu(W6) -> out. One WG (256 thr) per batch,
// thread-per-output dot products (W rows are L2-hot).
// ---------------------------------------------------------------------------
__global__ __launch_bounds__(256) void k_final(
    const float* __restrict__ s_glob,
    const float* __restrict__ W5, const float* __restrict__ b5,
    const float* __restrict__ W6, const float* __restrict__ b6,
    float* __restrict__ out)
{
    __shared__ float sh[128], t5[128];
    int b = blockIdx.x, tid = threadIdx.x;
    if (tid < 128) sh[tid] = s_glob[b * 128 + tid];
    __syncthreads();
    if (tid < 128) {
        const float* wr = W5 + (size_t)tid * 128;
        float acc = b5[tid];
        #pragma unroll
        for (int k = 0; k < 128; k += 4) {
            f32x4 wv = *(const f32x4*)(wr + k);
            f32x4 sv = *(const f32x4*)&sh[k];
            acc += wv[0]*sv[0] + wv[1]*sv[1] + wv[2]*sv[2] + wv[3]*sv[3];
        }
        t5[tid] = lrelu(acc);
    }
    __syncthreads();
    #pragma unroll
    for (int q = 0; q < 2; q++) {
        int o = q * 256 + tid;
        const float* wr = W6 + (size_t)o * 128;
        float acc = b6[o];
        #pragma unroll
        for (int k = 0; k < 128; k += 4) {
            f32x4 wv = *(const f32x4*)(wr + k);
            f32x4 tv = *(const f32x4*)&t5[k];
            acc += wv[0]*tv[0] + wv[1]*tv[1] + wv[2]*tv[2] + wv[3]*tv[3];
        }
        out[b * 512 + o] = lrelu(acc);
    }
}

// ---------------------------------------------------------------------------
extern "C" void kernel_launch(void* const* d_in, const int* in_sizes, int n_in,
                              void* d_out, int out_size, void* d_ws, size_t ws_size,
                              hipStream_t stream)
{
    const float* x      = (const float*)d_in[0];
    const float* h      = (const float*)d_in[1];
    const float* conv_w = (const float*)d_in[2];
    const float* conv_b = (const float*)d_in[3];
    const float* bn_g   = (const float*)d_in[4];
    const float* bn_b   = (const float*)d_in[5];
    const float* W1     = (const float*)d_in[6];
    const float* b1     = (const float*)d_in[7];
    const float* W2     = (const float*)d_in[8];
    const float* b2     = (const float*)d_in[9];
    const float* W3     = (const float*)d_in[10];
    const float* b3     = (const float*)d_in[11];
    const float* W4     = (const float*)d_in[12];
    const float* b4     = (const float*)d_in[13];
    const float* W5     = (const float*)d_in[14];
    const float* b5     = (const float*)d_in[15];
    const float* W6     = (const float*)d_in[16];
    const float* b6     = (const float*)d_in[17];

    char* ws = (char*)d_ws;
    float* s_glob = (float*)(ws + 0);          //  8 KB
    float* stats  = (float*)(ws + 8192);       //  2 KB
    float* hW     = (float*)(ws + 10240);      //  8 KB
    float* ws_y   = (float*)(ws + 18432);      //  2.62 MB
    float* vv     = (float*)(ws + 2639872);    //  1.31 MB
    float* uu     = (float*)(ws + 3950592);    //  1.31 MB
    u16*   xb     = (u16*)  (ws + 5261312);    //  2.62 MB
    u16*   wcb_f  = (u16*)  (ws + 7882752);    //  786 KB (frag order)
    u16*   wfrag  = (u16*)  (ws + 8669184);    //  110.6 KB
    u16*   w1frag = (u16*)  (ws + 8779776);    //  147.5 KB (end 8,927,232)

    k_prep <<<1729, 256, 0, stream>>>(x, conv_w, W2, W3, W4, b2, b3, b4, h, W1,
                                      xb, wcb_f, wfrag, w1frag, hW, s_glob);
    k_conv <<<640, 256, 0, stream>>>(xb, wcb_f, conv_b, ws_y, stats);
    k_uv   <<<160, 256, 0, stream>>>(ws_y, stats, bn_g, bn_b, w1frag, b1, hW, uu, vv);
    k_mlp  <<<3200, 256, 0, stream>>>(vv, uu, wfrag, s_glob);
    k_final<<<16, 256, 0, stream>>>(s_glob, W5, b5, W6, b6, (float*)d_out);
}